// Round 6
// baseline (142.439 us; speedup 1.0000x reference)
//
#include <hip/hip_runtime.h>

#define NROIS 512
#define NEDGES 262144

// ---------------------------------------------------------------------------
// edge_index may arrive as int64 (reference dtype) or int32 (harness downcast).
__device__ __forceinline__ int detect_i64(const unsigned* __restrict__ er) {
    unsigned acc = 0;
#pragma unroll
    for (int i = 0; i < 64; ++i) acc |= er[2 * i + 1];
    return acc == 0u;
}

__device__ __forceinline__ void load_edge(const unsigned* __restrict__ er,
                                          bool i64, int e, int& src, int& dst) {
    if (i64) { src = (int)er[2 * e]; dst = (int)er[2 * NEDGES + 2 * e]; }
    else     { src = (int)er[e];     dst = (int)er[NEDGES + e]; }
}

// ---------------------------------------------------------------------------
// hist: 256 blocks x 1024 edges, per-block LDS hist -> gpart[256][512]
__global__ __launch_bounds__(256) void hist_kernel(const unsigned* __restrict__ er,
                                                   int* __restrict__ gpart)
{
    __shared__ int lh[NROIS];
    __shared__ int s_l;
    const int t = threadIdx.x;
    if (t == 0) s_l = detect_i64(er);
    for (int i = t; i < NROIS; i += 256) lh[i] = 0;
    __syncthreads();
    const bool L = (s_l != 0);
    const int e0 = blockIdx.x * 1024;
#pragma unroll
    for (int k = 0; k < 4; ++k) {
        int e = e0 + k * 256 + t, src, dst;
        load_edge(er, L, e, src, dst);
        atomicAdd(&lh[dst], 1);
    }
    __syncthreads();
    for (int i = t; i < NROIS; i += 256) gpart[blockIdx.x * NROIS + i] = lh[i];
}

// scan: sum 256 partials per bin, inclusive scan -> start[513], cursor (exclusive)
__global__ __launch_bounds__(512) void scan_kernel(const int* __restrict__ gpart,
                                                   int* __restrict__ start,
                                                   int* __restrict__ cursor)
{
    __shared__ int tmp[NROIS];
    const int t = threadIdx.x;
    int own = 0;
#pragma unroll 8
    for (int b = 0; b < 256; ++b) own += gpart[b * NROIS + t];
    tmp[t] = own;
    __syncthreads();
    for (int off = 1; off < NROIS; off <<= 1) {
        int v = tmp[t];
        int add = (t >= off) ? tmp[t - off] : 0;
        __syncthreads();
        tmp[t] = v + add;
        __syncthreads();
    }
    start[t + 1] = tmp[t];
    if (t == 0) start[0] = 0;
    cursor[t] = tmp[t] - own;            // exclusive prefix
}

// scatter + fused pack: 256 blocks x 1024 edges. Per-block LDS bucketing, one
// global atomic per (block,bin). packed: eas rows only; else perm.
__global__ __launch_bounds__(256) void scatter_kernel(const unsigned* __restrict__ er,
                                                      const float* __restrict__ ea,
                                                      int* __restrict__ gcursor,
                                                      unsigned* __restrict__ perm,
                                                      float* __restrict__ eas,
                                                      int packed)
{
    __shared__ int lh[NROIS];
    __shared__ int lbase[NROIS];
    __shared__ int s_l;
    const int t = threadIdx.x;
    if (t == 0) s_l = detect_i64(er);
    for (int i = t; i < NROIS; i += 256) lh[i] = 0;
    __syncthreads();
    const bool L = (s_l != 0);
    const int e0 = blockIdx.x * 1024;
#pragma unroll
    for (int k = 0; k < 4; ++k) {
        int e = e0 + k * 256 + t, src, dst;
        load_edge(er, L, e, src, dst);
        atomicAdd(&lh[dst], 1);
    }
    __syncthreads();
    for (int i = t; i < NROIS; i += 256) {
        int c = lh[i];
        lbase[i] = c ? atomicAdd(&gcursor[i], c) : 0;
    }
    __syncthreads();
#pragma unroll
    for (int k = 0; k < 4; ++k) {
        int e = e0 + k * 256 + t, src, dst;
        load_edge(er, L, e, src, dst);
        int pos = atomicAdd(&lbase[dst], 1);
        unsigned ps = ((unsigned)e << 9) | (unsigned)src;
        if (packed) {
            const float2* s = reinterpret_cast<const float2*>(ea + (size_t)e * 6);
            const float2 a0 = s[0], a1 = s[1], a2 = s[2];
            float4* d = reinterpret_cast<float4*>(eas + (size_t)pos * 8);
            d[0] = make_float4(a0.x, a0.y, a1.x, a1.y);
            d[1] = make_float4(a2.x, a2.y, __uint_as_float(ps), 0.f);
        } else {
            perm[pos] = ps;
        }
    }
}

// ---------------------------------------------------------------------------
// per-edge attr fetch (packed rows of 8 floats, or fallback via perm+ea)
template <bool PACKED>
__device__ __forceinline__ void fetch_edge(const float* __restrict__ eas,
                                           const float* __restrict__ ea,
                                           const unsigned* __restrict__ perm,
                                           int idx, float a[6], unsigned& ps)
{
    if constexpr (PACKED) {
        const float4* ap4 = reinterpret_cast<const float4*>(eas + (size_t)idx * 8);
        const float4 r0 = ap4[0], r1 = ap4[1];
        a[0] = r0.x; a[1] = r0.y; a[2] = r0.z; a[3] = r0.w;
        a[4] = r1.x; a[5] = r1.y; ps = __float_as_uint(r1.z);
    } else {
        ps = perm[idx];
        const float* ap = ea + (size_t)(ps >> 9) * 6;
        a[0] = ap[0]; a[1] = ap[1]; a[2] = ap[2];
        a[3] = ap[3]; a[4] = ap[4]; a[5] = ap[5];
    }
}

__device__ __forceinline__ float edge_w(const float a[6], float wb, const float wv[6]) {
    float tt = wb;
    tt = fmaf(a[0], wv[0], tt);
    tt = fmaf(a[1], wv[1], tt);
    tt = fmaf(a[2], wv[2], tt);
    tt = fmaf(a[3], wv[3], tt);
    tt = fmaf(a[4], wv[4], tt);
    tt = fmaf(a[5], wv[5], tt);
    return fmaxf(tt, 0.f);
}

// ---------------------------------------------------------------------------
// Thread owns (i, NP o's); small NP so weights truly stay in VGPRs (the
// compiler sinks/remats large weight arrays back into the loop — rounds 4/5).
// grid = (SPLIT, NROIS); partial[chunk][dst][COUT]
template <int CIN, int COUT, int NP, int BLOCK, int SPLIT, bool PACKED>
__global__ __launch_bounds__(BLOCK) void edge_aggr_kernel(
    const float* __restrict__ eas, const float* __restrict__ ea,
    const unsigned* __restrict__ perm, const int* __restrict__ start,
    const float* __restrict__ lw, const float* __restrict__ lb,
    const float* __restrict__ hin, float* __restrict__ partial)
{
    constexpr int OGRP = COUT / NP;       // o-groups per i
    constexpr int TUSED = CIN * OGRP;     // active threads
    const int t = threadIdx.x;
    const int tc = (t < TUSED) ? t : 0;   // clamp: idle lanes shadow thread 0
    const int ii = tc / OGRP, og = tc % OGRP;

    float wb[NP], wv[NP][6];
#pragma unroll
    for (int p = 0; p < NP; ++p) {
        const int o = og * NP + p;
        wb[p] = lb[ii * COUT + o];
#pragma unroll
        for (int v = 0; v < 6; ++v) wv[p][v] = lw[v * (CIN * COUT) + ii * COUT + o];
    }

    const int dst = blockIdx.y, chunk = blockIdx.x;
    const int s0 = start[dst];
    const int cnt = start[dst + 1] - s0;
    const int c0 = s0 + (cnt * chunk) / SPLIT;
    const int c1 = s0 + (cnt * (chunk + 1)) / SPLIT;

    float acc[NP];
#pragma unroll
    for (int p = 0; p < NP; ++p) acc[p] = 0.f;

#pragma unroll 2
    for (int idx = c0; idx < c1; ++idx) {
        float a[6]; unsigned ps;
        fetch_edge<PACKED>(eas, ea, perm, idx, a, ps);
        const int src = (int)(ps & 511u);
        const float hsv = hin[src * CIN + ii];
#pragma unroll
        for (int p = 0; p < NP; ++p)
            acc[p] = fmaf(hsv, edge_w(a, wb[p], wv[p]), acc[p]);
    }

    __shared__ float red[CIN * COUT];
    if (t < TUSED) {
#pragma unroll
        for (int p = 0; p < NP; ++p) red[ii * COUT + og * NP + p] = acc[p];
    }
    __syncthreads();
    float* __restrict__ out = partial + ((size_t)chunk * NROIS + dst) * COUT;
    if (t < COUT) {
        float tot = 0.f;
#pragma unroll 4
        for (int k = 0; k < CIN; ++k) tot += red[k * COUT + t];
        out[t] = tot;
    }
}

// Layer-1 style (CIN==1): G edge-groups x COUT o's; group g walks edges
// c0+g, c0+g+G, ...
template <int COUT, int G, int BLOCK, int SPLIT, bool PACKED>
__global__ __launch_bounds__(BLOCK) void edge_aggr1_kernel(
    const float* __restrict__ eas, const float* __restrict__ ea,
    const unsigned* __restrict__ perm, const int* __restrict__ start,
    const float* __restrict__ lw, const float* __restrict__ lb,
    const float* __restrict__ hin, float* __restrict__ partial)
{
    constexpr int TUSED = G * COUT;
    const int t = threadIdx.x;
    const int tc = (t < TUSED) ? t : 0;
    const int g = tc / COUT, o = tc % COUT;

    float wb = lb[o], wv[6];
#pragma unroll
    for (int v = 0; v < 6; ++v) wv[v] = lw[v * COUT + o];

    const int dst = blockIdx.y, chunk = blockIdx.x;
    const int s0 = start[dst];
    const int cnt = start[dst + 1] - s0;
    const int c0 = s0 + (cnt * chunk) / SPLIT;
    const int c1 = s0 + (cnt * (chunk + 1)) / SPLIT;

    float acc = 0.f;
#pragma unroll 2
    for (int idx = c0 + g; idx < c1; idx += G) {
        float a[6]; unsigned ps;
        fetch_edge<PACKED>(eas, ea, perm, idx, a, ps);
        const float hsv = hin[(int)(ps & 511u)];
        acc = fmaf(hsv, edge_w(a, wb, wv), acc);
    }

    __shared__ float red[TUSED];
    if (t < TUSED) red[t] = acc;
    __syncthreads();
    float* __restrict__ out = partial + ((size_t)chunk * NROIS + dst) * COUT;
    if (t < COUT) {
        float tot = 0.f;
#pragma unroll
        for (int k = 0; k < G; ++k) tot += red[k * COUT + t];
        out[t] = tot;
    }
}

// combine chunks + mean + root term + bias + relu
template <int CIN, int COUT, int SPLIT>
__global__ __launch_bounds__(256) void node_kernel(
    const float* __restrict__ hin, const float* __restrict__ partial,
    const int* __restrict__ start, const float* __restrict__ root,
    const float* __restrict__ bias, float* __restrict__ hout)
{
    int t = blockIdx.x * 256 + threadIdx.x;
    if (t >= NROIS * COUT) return;
    int i = t / COUT, o = t - i * COUT;
    float s = 0.f;
#pragma unroll
    for (int c = 0; c < SPLIT; ++c) s += partial[((size_t)c * NROIS + i) * COUT + o];
    int cnt = start[i + 1] - start[i];
    float aggr = s / fmaxf((float)cnt, 1.f);
    float r = bias[o];
#pragma unroll 4
    for (int k = 0; k < CIN; ++k) r = fmaf(hin[i * CIN + k], root[k * COUT + o], r);
    hout[t] = fmaxf(aggr + r, 0.f);
}

// cbt[i,j] = sum_k |h[i,k]-h[j,k]|, h: [512,5] staged in LDS, block per row i
__global__ __launch_bounds__(256) void cbt_kernel(const float* __restrict__ h,
                                                  float* __restrict__ out)
{
    __shared__ float sh[NROIS * 5];
    for (int t = threadIdx.x; t < NROIS * 5; t += 256) sh[t] = h[t];
    __syncthreads();
    const int i = blockIdx.x;
    float hi[5];
#pragma unroll
    for (int k = 0; k < 5; ++k) hi[k] = sh[i * 5 + k];
    for (int j = threadIdx.x; j < NROIS; j += 256) {
        float s = 0.f;
#pragma unroll
        for (int k = 0; k < 5; ++k) s += fabsf(hi[k] - sh[j * 5 + k]);
        out[i * NROIS + j] = s;
    }
}

// ---------------------------------------------------------------------------
template <bool PACKED>
static void run_layers(const float* x, const float* ea,
                       const float* lw1, const float* lb1, const float* root1, const float* b1,
                       const float* lw2, const float* lb2, const float* root2, const float* b2,
                       const float* lw3, const float* lb3, const float* root3, const float* b3,
                       const float* eas, const unsigned* perm, const int* start,
                       float* part, float* h1, float* h2, float* h3,
                       hipStream_t stream)
{
    // layer 1: cin=1, cout=36 (G=7 edge groups x 36 o's)
    edge_aggr1_kernel<36, 7, 256, 8, PACKED><<<dim3(8, NROIS), 256, 0, stream>>>(
        eas, ea, perm, start, lw1, lb1, x, part);
    node_kernel<1, 36, 8><<<(NROIS * 36 + 255) / 256, 256, 0, stream>>>(
        x, part, start, root1, b1, h1);
    // layer 2: cin=36, cout=24, NP=2 (14 weight floats/thread -> stays in VGPR)
    edge_aggr_kernel<36, 24, 2, 448, 4, PACKED><<<dim3(4, NROIS), 448, 0, stream>>>(
        eas, ea, perm, start, lw2, lb2, h1, part);
    node_kernel<36, 24, 4><<<(NROIS * 24 + 255) / 256, 256, 0, stream>>>(
        h1, part, start, root2, b2, h2);
    // layer 3: cin=24, cout=5, NP=1 (7 weight floats/thread)
    edge_aggr_kernel<24, 5, 1, 128, 4, PACKED><<<dim3(4, NROIS), 128, 0, stream>>>(
        eas, ea, perm, start, lw3, lb3, h2, part);
    node_kernel<24, 5, 4><<<(NROIS * 5 + 255) / 256, 256, 0, stream>>>(
        h2, part, start, root3, b3, h3);
}

extern "C" void kernel_launch(void* const* d_in, const int* in_sizes, int n_in,
                              void* d_out, int out_size, void* d_ws, size_t ws_size,
                              hipStream_t stream)
{
    const float*    x     = (const float*)d_in[0];
    const float*    ea    = (const float*)d_in[1];
    const unsigned* er    = (const unsigned*)d_in[2];
    const float*    lw1   = (const float*)d_in[3];
    const float*    lb1   = (const float*)d_in[4];
    const float*    root1 = (const float*)d_in[5];
    const float*    b1    = (const float*)d_in[6];
    const float*    lw2   = (const float*)d_in[7];
    const float*    lb2   = (const float*)d_in[8];
    const float*    root2 = (const float*)d_in[9];
    const float*    b2    = (const float*)d_in[10];
    const float*    lw3   = (const float*)d_in[11];
    const float*    lb3   = (const float*)d_in[12];
    const float*    root3 = (const float*)d_in[13];
    const float*    b3    = (const float*)d_in[14];

    const size_t easN  = (size_t)NEDGES * 8;                 // floats
    const size_t restN = 18432 + 12288 + 2560 + 147456 + 513 + 512 + NEDGES;
    const size_t needPacked = (easN + restN) * 4;
    const int packed = (ws_size >= needPacked) ? 1 : 0;

    float* ws   = (float*)d_ws;
    float* eas  = ws;                                  // 8 MB (packed mode only)
    float* rest = packed ? (ws + easN) : ws;
    float* h1   = rest;                 // 512*36
    float* h2   = h1 + NROIS * 36;      // 512*24
    float* h3   = h2 + NROIS * 24;      // 512*5
    float* part = h3 + NROIS * 5;       // 147456 floats (also gpart scratch)
    int* gpart  = (int*)part;           // 256*512 ints (512 KB), pre-layer only
    int* start  = (int*)(part + 147456);
    int* cursor = start + NROIS + 1;    // 512
    unsigned* perm = (unsigned*)(cursor + NROIS);      // 262144

    // --- counting sort by dst + fused edge-attr pack (reused by all layers) ---
    hist_kernel<<<NEDGES / 1024, 256, 0, stream>>>(er, gpart);
    scan_kernel<<<1, 512, 0, stream>>>(gpart, start, cursor);
    scatter_kernel<<<NEDGES / 1024, 256, 0, stream>>>(er, ea, cursor, perm, eas, packed);

    if (packed)
        run_layers<true>(x, ea, lw1, lb1, root1, b1, lw2, lb2, root2, b2,
                         lw3, lb3, root3, b3, eas, perm, start, part, h1, h2, h3, stream);
    else
        run_layers<false>(x, ea, lw1, lb1, root1, b1, lw2, lb2, root2, b2,
                          lw3, lb3, root3, b3, eas, perm, start, part, h1, h2, h3, stream);

    // --- pairwise L1 distance tail ---
    cbt_kernel<<<NROIS, 256, 0, stream>>>(h3, (float*)d_out);
}